// Round 4
// baseline (264.539 us; speedup 1.0000x reference)
//
#include <hip/hip_runtime.h>

// ---------------------------------------------------------------------------
// Attention_5978594476296: B=2,S=2048,D=1024,H=16,DK=64
// k_pre -> k_qkv (32x32x16 MFMA bt-GEMM; K,V emitted in MFMA-ready packed
// fragment order; Q pre-scaled) -> k_attn (no-staging flash: packed coalesced
// dwordx4 operand loads, 2 q-tiles x 2 k-halves per block, XCD-affine block
// mapping (bh on blockIdx.x -> all q-blocks of a bh share one XCD L2),
// one-iter K-fragment prefetch, raw v_exp_f32 softmax, permlane32_swap
// P-packing, fdot2 row-sum, setprio around MFMA) -> k_oproj -> f32 out
// R1 lesson: per-wave state ~128 regs -> 4 waves/SIMD ceiling; forcing 8/EU
//   spills accumulators (FETCH 69MB->1.1GB). Keep VGPR < 128 under LB(256,4).
// R2 lesson: VALUBusy 59% was ~70% libm exp2f expansion + st zero-init.
// R3 lesson: VALU diet verified (31% busy) but wall barely moved -> 44% of
//   cycles were load-latency stall + 8x XCD K/V re-fetch (70MB vs 25 ideal).
// ---------------------------------------------------------------------------

typedef _Float16 f16x8 __attribute__((ext_vector_type(8)));
typedef _Float16 f16x4 __attribute__((ext_vector_type(4)));
typedef _Float16 f16x2 __attribute__((ext_vector_type(2)));
typedef float    f32x4 __attribute__((ext_vector_type(4)));
typedef float    f32x16 __attribute__((ext_vector_type(16)));
typedef int      i32x4 __attribute__((ext_vector_type(4)));
typedef unsigned u32x2 __attribute__((ext_vector_type(2)));

#define MFMA32(a, b, c) __builtin_amdgcn_mfma_f32_32x32x16_f16(a, b, c, 0, 0, 0)
#define MFMA16(a, b, c) __builtin_amdgcn_mfma_f32_16x16x32_f16(a, b, c, 0, 0, 0)

#if __has_builtin(__builtin_amdgcn_exp2f)
#define EXP2(x) __builtin_amdgcn_exp2f(x)
#else
#define EXP2(x) exp2f(x)
#endif

__device__ __forceinline__ void gld16(const void* g, void* l) {
    __builtin_amdgcn_global_load_lds(
        (const __attribute__((address_space(1))) void*)g,
        (__attribute__((address_space(3))) void*)l, 16, 0, 0);
}

// ---------------- fused preprocessing: 5 convs + mask scan ------------------
__device__ __forceinline__ void conv1k(const float* __restrict__ in,
                                       _Float16* __restrict__ out, int base) {
    const int i = base + threadIdx.x * 4;
    float4 v = *(const float4*)(in + i);
    f16x4 o;
    o.x = (_Float16)v.x; o.y = (_Float16)v.y; o.z = (_Float16)v.z; o.w = (_Float16)v.w;
    *(f16x4*)(out + i) = o;
}

__global__ void k_pre(const float* __restrict__ X, const float* __restrict__ Wq,
                      const float* __restrict__ Wk, const float* __restrict__ Wv,
                      const float* __restrict__ Wo,
                      _Float16* __restrict__ Xh, _Float16* __restrict__ Wqh,
                      _Float16* __restrict__ Wkh, _Float16* __restrict__ Wvh,
                      _Float16* __restrict__ Woh,
                      const int* __restrict__ mask, int* __restrict__ flag) {
    const int bid = blockIdx.x;
    if (bid < 4096)      conv1k(X,  Xh,  bid * 1024);
    else if (bid < 5120) conv1k(Wq, Wqh, (bid - 4096) * 1024);
    else if (bid < 6144) conv1k(Wk, Wkh, (bid - 5120) * 1024);
    else if (bid < 7168) conv1k(Wv, Wvh, (bid - 6144) * 1024);
    else if (bid < 8192) conv1k(Wo, Woh, (bid - 7168) * 1024);
    else {
        const int i = (bid - 8192) * 1024 + threadIdx.x * 4;
        int4 v = *(const int4*)(mask + i);
        if ((v.x == 0) | (v.y == 0) | (v.z == 0) | (v.w == 0)) atomicOr(flag, 1);
    }
}

// --------------------- fused QKV projection (bt-GEMM) -----------------------
// Q out: (B,H,S,DK), pre-scaled by 0.125*log2e.
// K out: packed A-frag order Kp[bh][s>>5][dk>>4][(s&31)+32*((dk>>3)&1)][dk&7]
// V out: packed B-frag order Vp[bh][s>>4][dk>>5][(dk&31)+32*((s>>3)&1)][s&7]
__global__ __launch_bounds__(256, 3) void k_qkv(
    const _Float16* __restrict__ X,
    const _Float16* __restrict__ Wqh, const _Float16* __restrict__ Wkh,
    const _Float16* __restrict__ Wvh,
    const float* __restrict__ bq, const float* __restrict__ bk,
    const float* __restrict__ bv,
    _Float16* __restrict__ Qo, _Float16* __restrict__ Ko, _Float16* __restrict__ Vo)
{
    __shared__ _Float16 SH[128 * 136];          // staging (As|Bs) + epilogue buffer
    _Float16* As = SH;                          // 128*64
    _Float16* Bs = SH + 128 * 64;               // 128*64
    const int tid = threadIdx.x;
    const int lane = tid & 63, wv = tid >> 6;
    const int wrow = wv >> 1, wcol = wv & 1;
    const int l5 = lane & 31, half = lane >> 5;
    const int which = blockIdx.x >> 3;
    const _Float16* W   = which == 0 ? Wqh : which == 1 ? Wkh : Wvh;
    const float*   bias = which == 0 ? bq  : which == 1 ? bk  : bv;
    const int n0 = (blockIdx.x & 7) * 128;
    const int m0 = blockIdx.y * 128;

    f32x16 acc[2][2];
#pragma unroll
    for (int a = 0; a < 2; ++a)
#pragma unroll
        for (int bb = 0; bb < 2; ++bb)
#pragma unroll
            for (int r = 0; r < 16; ++r) acc[a][bb][r] = 0.f;

#pragma unroll 1
    for (int k0 = 0; k0 < 1024; k0 += 64) {
        __syncthreads();
#pragma unroll
        for (int it = 0; it < 4; ++it) {
            const int wbase = it * 256 + wv * 64;
            const int ci = wbase + lane;
            const int r = ci >> 3;
            const int c8 = (((ci & 7) ^ (r & 7)) * 8);   // XOR-swizzled gather
            gld16(X + (size_t)(m0 + r) * 1024 + k0 + c8, As + wbase * 8);
            gld16(W + (size_t)(n0 + r) * 1024 + k0 + c8, Bs + wbase * 8);
        }
        __syncthreads();
#pragma unroll
        for (int ks = 0; ks < 4; ++ks) {
            f16x8 af[2], bf[2];
#pragma unroll
            for (int mt = 0; mt < 2; ++mt)
                af[mt] = *(const f16x8*)(As + (wrow * 64 + mt * 32 + l5) * 64 +
                                         (((ks * 2 + half) ^ (l5 & 7)) * 8));
#pragma unroll
            for (int nt = 0; nt < 2; ++nt)
                bf[nt] = *(const f16x8*)(Bs + (wcol * 64 + nt * 32 + l5) * 64 +
                                         (((ks * 2 + half) ^ (l5 & 7)) * 8));
#pragma unroll
            for (int mt = 0; mt < 2; ++mt)
#pragma unroll
                for (int nt = 0; nt < 2; ++nt)
                    acc[mt][nt] = MFMA32(af[mt], bf[nt], acc[mt][nt]);
        }
    }

    __syncthreads();   // staging dead; reuse SH for epilogue transpose
    const int b_ = m0 >> 11;
    const int s_base = m0 & 2047;
    // C/D: col = l5 (n/e dim), row = (reg&3)+8*(reg>>2)+4*half (m/s dim)
    if (which == 2) {
        // V: SH[e_l * 136 + m_l] (transposed)
#pragma unroll
        for (int nt = 0; nt < 2; ++nt) {
            const int e_l = wcol * 64 + nt * 32 + l5;
            const float bv_ = bias[n0 + e_l];
#pragma unroll
            for (int mt = 0; mt < 2; ++mt)
#pragma unroll
                for (int g = 0; g < 4; ++g) {
                    const int m_l = wrow * 64 + mt * 32 + 8 * g + 4 * half;
                    f16x4 pk;
#pragma unroll
                    for (int j = 0; j < 4; ++j)
                        pk[j] = (_Float16)(acc[mt][nt][4 * g + j] + bv_);
                    *(f16x4*)(SH + e_l * 136 + m_l) = pk;
                }
        }
        __syncthreads();
#pragma unroll
        for (int p = 0; p < 8; ++p) {
            const int e_l = p * 16 + (tid >> 4);
            const int s8 = (tid & 15) * 8;
            f16x8 vv = *(const f16x8*)(SH + e_l * 136 + s8);
            const int e = n0 + e_l;
            const int h = e >> 6, dk = e & 63;
            const int s0 = s_base + s8;
            // Vp[bh][s0>>4][dk>>5][(dk&31)+32*((s8>>3)&1)][s&7]
            const size_t idx = ((((size_t)(b_ * 16 + h) * 128 + (s0 >> 4)) * 2 +
                                (dk >> 5)) * 64 + (dk & 31) + 32 * ((s8 >> 3) & 1)) * 8;
            *(f16x8*)(Vo + idx) = vv;
        }
    } else {
        const float qs = (which == 0) ? 0.18033688011112042f : 1.0f;  // 0.125*log2e
#pragma unroll
        for (int nt = 0; nt < 2; ++nt) {
            const int e_l = wcol * 64 + nt * 32 + l5;
            const float bv_ = bias[n0 + e_l];
#pragma unroll
            for (int mt = 0; mt < 2; ++mt)
#pragma unroll
                for (int r = 0; r < 16; ++r) {
                    const int m_l = wrow * 64 + mt * 32 + (r & 3) + 8 * (r >> 2) + 4 * half;
                    SH[m_l * 136 + e_l] = (_Float16)((acc[mt][nt][r] + bv_) * qs);
                }
        }
        __syncthreads();
#pragma unroll
        for (int p = 0; p < 8; ++p) {
            const int m_l = p * 16 + (tid >> 4);
            const int c8 = (tid & 15) * 8;
            f16x8 vv = *(const f16x8*)(SH + m_l * 136 + c8);
            const int e = n0 + c8;
            const int h = e >> 6, dk = e & 63;
            const int s = s_base + m_l;
            if (which == 0) {
                *(f16x8*)(Qo + (((size_t)b_ * 16 + h) * 2048 + s) * 64 + dk) = vv;
            } else {
                // Kp[bh][s>>5][dk>>4][(s&31)+32*((dk>>3)&1)][dk&7]
                const size_t idx = ((((size_t)(b_ * 16 + h) * 64 + (s >> 5)) * 4 +
                                    (dk >> 4)) * 64 + (s & 31) + 32 * ((dk >> 3) & 1)) * 8;
                *(f16x8*)(Ko + idx) = vv;
            }
        }
    }
}

// --------------------------- output projection ------------------------------
__global__ __launch_bounds__(256, 4) void k_oproj(
    const _Float16* __restrict__ Oin, const _Float16* __restrict__ Woh,
    const float* __restrict__ bo, float* __restrict__ out)
{
    __shared__ _Float16 As[128 * 64];
    __shared__ _Float16 Bs[64 * 64];
    const int tid = threadIdx.x;
    const int lane = tid & 63, wv = tid >> 6;
    const int quad = lane >> 4, lc = lane & 15;
    const int n0 = blockIdx.x * 64;
    const int m0 = blockIdx.y * 128;

    const f32x4 fzero = {0.f, 0.f, 0.f, 0.f};
    f32x4 acc[2][4];
#pragma unroll
    for (int a = 0; a < 2; ++a)
#pragma unroll
        for (int bb = 0; bb < 4; ++bb) acc[a][bb] = fzero;

#pragma unroll 1
    for (int k0 = 0; k0 < 1024; k0 += 64) {
        __syncthreads();
#pragma unroll
        for (int it = 0; it < 4; ++it) {
            const int ci = it * 256 + tid;
            const int r = ci >> 3;
            const int c8 = (((ci & 7) ^ (r & 7)) * 8);
            gld16(Oin + (size_t)(m0 + r) * 1024 + k0 + c8, As + ci * 8);
        }
#pragma unroll
        for (int it = 0; it < 2; ++it) {
            const int ci = it * 256 + tid;
            const int r = ci >> 3;
            const int c8 = (((ci & 7) ^ (r & 7)) * 8);
            gld16(Woh + (size_t)(n0 + r) * 1024 + k0 + c8, Bs + ci * 8);
        }
        __syncthreads();
#pragma unroll
        for (int ks = 0; ks < 2; ++ks) {
            f16x8 af[2], bf[4];
#pragma unroll
            for (int mt = 0; mt < 2; ++mt)
                af[mt] = *(const f16x8*)(As + (wv * 32 + mt * 16 + lc) * 64 +
                                         (((ks * 4 + quad) ^ (lc & 7)) * 8));
#pragma unroll
            for (int nt = 0; nt < 4; ++nt)
                bf[nt] = *(const f16x8*)(Bs + (nt * 16 + lc) * 64 +
                                         (((ks * 4 + quad) ^ (lc & 7)) * 8));
#pragma unroll
            for (int mt = 0; mt < 2; ++mt)
#pragma unroll
                for (int nt = 0; nt < 4; ++nt)
                    acc[mt][nt] = MFMA16(af[mt], bf[nt], acc[mt][nt]);
        }
    }
#pragma unroll
    for (int nt = 0; nt < 4; ++nt) {
        const int e = n0 + nt * 16 + lc;
        const float bv_ = bo[e];
#pragma unroll
        for (int mt = 0; mt < 2; ++mt)
#pragma unroll
            for (int i = 0; i < 4; ++i) {
                const int m = m0 + wv * 32 + mt * 16 + quad * 4 + i;
                out[(size_t)m * 1024 + e] = acc[mt][nt][i] + bv_;
            }
    }
}

// ----------------------------- flash attention ------------------------------
// 256 thr / 4 waves = 2 q-tiles x 2 k-halves. Wave (qt,kh) computes q-tile
// [blockIdx.y*64 + qt*32, +32) over k-half [kh*1024, +1024) — 32 iters.
// XCD affinity: bh rides blockIdx.x (fastest) -> flattened id = bh + 32*q
// -> XCD = bh%8 for every q-block (32q % 8 == 0). Each XCD L2 then holds
// 4 bh x 512KB = 2MB of K/V (fits 4MB), killing the 8x cross-XCD re-fetch.
// K-fragment prefetched one iter ahead (kfc/kfn rotation, +16 VGPR); V loads
// issued at iter top get QK+softmax as latency cover. No in-loop barriers.
__global__ __launch_bounds__(256, 4) void k_attn(
    const _Float16* __restrict__ Q, const _Float16* __restrict__ Kp,
    const _Float16* __restrict__ Vp, const int* __restrict__ mask,
    const int* __restrict__ flag, _Float16* __restrict__ O)
{
    __shared__ float Os[2][32 * 64];   // partial O from kh==1 waves (16 KB)
    __shared__ float Ls[2][32];        // partial l from kh==1 waves

    const int tid = threadIdx.x;
    const int lane = tid & 63, wv = tid >> 6;
    const int l5 = lane & 31, half = lane >> 5;
    const int qt = wv >> 1, kh = wv & 1;
    const int bh = blockIdx.x;               // XCD-affine: bh -> XCD bh%8
    const int b = bh >> 4, h = bh & 15;
    const int qb = blockIdx.y * 64 + qt * 32;

    const _Float16* Qb = Q  + (size_t)bh * 2048 * 64;
    const _Float16* Kb = Kp + (size_t)bh * 131072;   // 64 kblk * 4 kk * 64 * 8
    const _Float16* Vb = Vp + (size_t)bh * 131072;   // 128 kblk * 2 nt * 64 * 8

    // Q fragments (B operand of S^T = K*Q^T): n=q=l5, k(dk)=kk*16+half*8+t
    f16x8 qf[4];
#pragma unroll
    for (int kk = 0; kk < 4; ++kk)
        qf[kk] = *(const f16x8*)(Qb + (size_t)(qb + l5) * 64 + kk * 16 + half * 8);

    const f32x16 fz = {0.f, 0.f, 0.f, 0.f, 0.f, 0.f, 0.f, 0.f,
                       0.f, 0.f, 0.f, 0.f, 0.f, 0.f, 0.f, 0.f};
    const f16x2 one2 = {(_Float16)1.f, (_Float16)1.f};

    f32x16 o[2];
#pragma unroll
    for (int nt = 0; nt < 2; ++nt)
#pragma unroll
        for (int r = 0; r < 16; ++r) o[nt][r] = 0.f;
    float l_i = 0.f;

    const bool has_zero = (*flag != 0);

    // ---- prologue: K fragments for first iteration ----
    f16x8 kfc[4];
#pragma unroll
    for (int kk = 0; kk < 4; ++kk)
        kfc[kk] = *(const f16x8*)(Kb + ((size_t)((kh * 32) * 4 + kk) * 64 + lane) * 8);

#pragma unroll 2
    for (int it = 0; it < 32; ++it) {
        const int kb = kh * 32 + it;
        // V fragments for current iter: used after softmax (QK+SM = cover)
        f16x8 vf[4];
#pragma unroll
        for (int ks = 0; ks < 2; ++ks)
#pragma unroll
            for (int nt = 0; nt < 2; ++nt)
                vf[ks * 2 + nt] = *(const f16x8*)(Vb +
                    ((size_t)((kb * 2 + ks) * 2 + nt) * 64 + lane) * 8);
        // K prefetch for next iter (wraps harmlessly on last iter)
        const int nkb = kh * 32 + ((it + 1) & 31);
        f16x8 kfn[4];
#pragma unroll
        for (int kk = 0; kk < 4; ++kk)
            kfn[kk] = *(const f16x8*)(Kb + ((size_t)(nkb * 4 + kk) * 64 + lane) * 8);

        // ---- S^T = K * Q^T ---- (kfc issued one full iteration ago)
        __builtin_amdgcn_s_setprio(1);
        f32x16 st = MFMA32(kfc[0], qf[0], fz);
        st = MFMA32(kfc[1], qf[1], st);
        st = MFMA32(kfc[2], qf[2], st);
        st = MFMA32(kfc[3], qf[3], st);
        __builtin_amdgcn_s_setprio(0);

        if (has_zero) {  // never taken for all-ones mask
            const int q = qb + l5;
            const int* mr = mask + ((size_t)b * 2048 + q) * 2048 + kb * 32;
            for (int r = 0; r < 16; ++r) {
                const int kk_ = (r & 3) + 8 * (r >> 2) + 4 * half;
                if (mr[kk_] == 0) st[r] = -1e30f;
            }
        }

        // ---- shift-free exp2 softmax: raw v_exp_f32 + pack + fdot2 sum ----
        unsigned u[8];
        float rs = 0.f;
#pragma unroll
        for (int j = 0; j < 8; ++j) {
            const float p0 = EXP2(st[2 * j]);
            const float p1 = EXP2(st[2 * j + 1]);
            u[j] = __builtin_bit_cast(unsigned, __builtin_amdgcn_cvt_pkrtz(p0, p1));
#if __has_builtin(__builtin_amdgcn_fdot2)
            rs = __builtin_amdgcn_fdot2(__builtin_bit_cast(f16x2, u[j]), one2, rs, false);
#else
            rs += p0 + p1;
#endif
        }
        rs += __shfl_xor(rs, 32);   // combine lane-halves (same q)
        l_i += rs;

        // ---- P: C-layout -> A-operand via permlane32_swap half-swap ----
        // swap(A,B): out0 = [A.lo, B.lo], out1 = [A.hi, B.hi]
        u32x2 r02 = __builtin_amdgcn_permlane32_swap(u[0], u[2], false, false);
        u32x2 r13 = __builtin_amdgcn_permlane32_swap(u[1], u[3], false, false);
        u32x2 r46 = __builtin_amdgcn_permlane32_swap(u[4], u[6], false, false);
        u32x2 r57 = __builtin_amdgcn_permlane32_swap(u[5], u[7], false, false);
        i32x4 a0 = { (int)r02[0], (int)r13[0], (int)r02[1], (int)r13[1] };
        i32x4 a1 = { (int)r46[0], (int)r57[0], (int)r46[1], (int)r57[1] };
        f16x8 pa0 = __builtin_bit_cast(f16x8, a0);
        f16x8 pa1 = __builtin_bit_cast(f16x8, a1);

        // ---- O += P * V ----
        __builtin_amdgcn_s_setprio(1);
        o[0] = MFMA32(pa0, vf[0], o[0]);
        o[1] = MFMA32(pa0, vf[1], o[1]);
        o[0] = MFMA32(pa1, vf[2], o[0]);
        o[1] = MFMA32(pa1, vf[3], o[1]);
        __builtin_amdgcn_s_setprio(0);

        // rotate prefetched K into place (renamed away by unroll 2)
#pragma unroll
        for (int kk = 0; kk < 4; ++kk) kfc[kk] = kfn[kk];
    }

    // ---- merge k-half partials via LDS (single barrier), normalize, store --
    if (kh == 1) {
        if (half == 0) Ls[qt][l5] = l_i;
#pragma unroll
        for (int nt = 0; nt < 2; ++nt)
#pragma unroll
            for (int r = 0; r < 16; ++r) {
                const int q_loc = (r & 3) + 8 * (r >> 2) + 4 * half;
                Os[qt][q_loc * 64 + nt * 32 + l5] = o[nt][r];
            }
    }
    __syncthreads();
    if (kh == 0) {
        const float linv = 1.f / (l_i + Ls[qt][l5]);   // l indexed by q=l5
#pragma unroll
        for (int r = 0; r < 16; ++r) {
            const int q_loc = (r & 3) + 8 * (r >> 2) + 4 * half;
            const float lv = __shfl(linv, q_loc);
            const int q = qb + q_loc;
            _Float16* orow = O + ((size_t)b * 2048 + q) * 1024 + h * 64;
#pragma unroll
            for (int nt = 0; nt < 2; ++nt) {
                const float val = o[nt][r] + Os[qt][q_loc * 64 + nt * 32 + l5];
                orow[nt * 32 + l5] = (_Float16)(val * lv);
            }
        }
    }
}

// ---------------------------------------------------------------------------
extern "C" void kernel_launch(void* const* d_in, const int* in_sizes, int n_in,
                              void* d_out, int out_size, void* d_ws, size_t ws_size,
                              hipStream_t stream) {
    const float* query = (const float*)d_in[0];
    const int*   mask  = (const int*)d_in[1];
    const float* Wq = (const float*)d_in[2]; const float* bq = (const float*)d_in[3];
    const float* Wk = (const float*)d_in[4]; const float* bk = (const float*)d_in[5];
    const float* Wv = (const float*)d_in[6]; const float* bv = (const float*)d_in[7];
    const float* Wo = (const float*)d_in[8]; const float* bo = (const float*)d_in[9];
    float* out = (float*)d_out;

    char* ws = (char*)d_ws;
    _Float16* Xh  = (_Float16*)(ws);                 // 4096x1024, reused as Oh
    _Float16* Wqh = (_Float16*)(ws + 8388608);
    _Float16* Wkh = (_Float16*)(ws + 10485760);
    _Float16* Wvh = (_Float16*)(ws + 12582912);
    _Float16* Woh = (_Float16*)(ws + 14680064);
    _Float16* Qh  = (_Float16*)(ws + 16777216);
    _Float16* Kh  = (_Float16*)(ws + 25165824);      // packed Kp
    _Float16* Vh  = (_Float16*)(ws + 33554432);      // packed Vp
    _Float16* Oh  = Xh;
    int* flag     = (int*)(ws + 41943040);

    (void)hipMemsetAsync(flag, 0, 4, stream);
    k_pre<<<16384, 256, 0, stream>>>(query, Wq, Wk, Wv, Wo,
                                     Xh, Wqh, Wkh, Wvh, Woh, mask, flag);
    k_qkv<<<dim3(24, 32), 256, 0, stream>>>(Xh, Wqh, Wkh, Wvh, bq, bk, bv, Qh, Kh, Vh);
    k_attn<<<dim3(32, 32), 256, 0, stream>>>(Qh, Kh, Vh, mask, flag, Oh);
    k_oproj<<<dim3(16, 32), 256, 0, stream>>>(Oh, Woh, bo, out);
}

// Round 5
// 214.449 us; speedup vs baseline: 1.2336x; 1.2336x over previous
//
#include <hip/hip_runtime.h>

// ---------------------------------------------------------------------------
// Attention_5978594476296: B=2,S=2048,D=1024,H=16,DK=64
// k_pre -> k_qkv (32x32x16 MFMA bt-GEMM; K,V emitted in MFMA-ready packed
// fragment order; Q pre-scaled) -> k_attn (no-staging flash: packed coalesced
// dwordx4 operand loads, 2 q-tiles x 2 k-halves per block, XCD-affine block
// mapping (bh on blockIdx.x -> all q-blocks of a bh share one XCD L2),
// raw v_exp_f32 softmax, permlane32_swap P-packing, fdot2 row-sum,
// setprio around MFMA) -> k_oproj -> f32 out
// R1 lesson: per-wave state ~128 regs -> 4 waves/SIMD ceiling; forcing 8/EU
//   spills accumulators (FETCH 69MB->1.1GB).
// R2 lesson: VALUBusy 59% was ~70% libm exp2f expansion + st zero-init.
// R3 lesson: VALU diet verified (31% busy) but wall barely moved -> stall is
//   load latency + 8x XCD K/V re-fetch (70MB vs 25 ideal).
// R4 lesson: XCD-affinity works (FETCH 70->23MB, keep). K-prefetch (+16 reg)
//   crossed the unified-file budget -> scratch spill (WRITE 10->30MB, 2x
//   wall). VGPR_Count only reports arch VGPRs — watch WRITE_SIZE for spills.
// ---------------------------------------------------------------------------

typedef _Float16 f16x8 __attribute__((ext_vector_type(8)));
typedef _Float16 f16x4 __attribute__((ext_vector_type(4)));
typedef _Float16 f16x2 __attribute__((ext_vector_type(2)));
typedef float    f32x4 __attribute__((ext_vector_type(4)));
typedef float    f32x16 __attribute__((ext_vector_type(16)));
typedef int      i32x4 __attribute__((ext_vector_type(4)));
typedef unsigned u32x2 __attribute__((ext_vector_type(2)));

#define MFMA32(a, b, c) __builtin_amdgcn_mfma_f32_32x32x16_f16(a, b, c, 0, 0, 0)
#define MFMA16(a, b, c) __builtin_amdgcn_mfma_f32_16x16x32_f16(a, b, c, 0, 0, 0)

#if __has_builtin(__builtin_amdgcn_exp2f)
#define EXP2(x) __builtin_amdgcn_exp2f(x)
#else
#define EXP2(x) exp2f(x)
#endif

__device__ __forceinline__ void gld16(const void* g, void* l) {
    __builtin_amdgcn_global_load_lds(
        (const __attribute__((address_space(1))) void*)g,
        (__attribute__((address_space(3))) void*)l, 16, 0, 0);
}

// ---------------- fused preprocessing: 5 convs + mask scan ------------------
__device__ __forceinline__ void conv1k(const float* __restrict__ in,
                                       _Float16* __restrict__ out, int base) {
    const int i = base + threadIdx.x * 4;
    float4 v = *(const float4*)(in + i);
    f16x4 o;
    o.x = (_Float16)v.x; o.y = (_Float16)v.y; o.z = (_Float16)v.z; o.w = (_Float16)v.w;
    *(f16x4*)(out + i) = o;
}

__global__ void k_pre(const float* __restrict__ X, const float* __restrict__ Wq,
                      const float* __restrict__ Wk, const float* __restrict__ Wv,
                      const float* __restrict__ Wo,
                      _Float16* __restrict__ Xh, _Float16* __restrict__ Wqh,
                      _Float16* __restrict__ Wkh, _Float16* __restrict__ Wvh,
                      _Float16* __restrict__ Woh,
                      const int* __restrict__ mask, int* __restrict__ flag) {
    const int bid = blockIdx.x;
    if (bid < 4096)      conv1k(X,  Xh,  bid * 1024);
    else if (bid < 5120) conv1k(Wq, Wqh, (bid - 4096) * 1024);
    else if (bid < 6144) conv1k(Wk, Wkh, (bid - 5120) * 1024);
    else if (bid < 7168) conv1k(Wv, Wvh, (bid - 6144) * 1024);
    else if (bid < 8192) conv1k(Wo, Woh, (bid - 7168) * 1024);
    else {
        const int i = (bid - 8192) * 1024 + threadIdx.x * 4;
        int4 v = *(const int4*)(mask + i);
        if ((v.x == 0) | (v.y == 0) | (v.z == 0) | (v.w == 0)) atomicOr(flag, 1);
    }
}

// --------------------- fused QKV projection (bt-GEMM) -----------------------
// Q out: (B,H,S,DK), pre-scaled by 0.125*log2e.
// K out: packed A-frag order Kp[bh][s>>5][dk>>4][(s&31)+32*((dk>>3)&1)][dk&7]
// V out: packed B-frag order Vp[bh][s>>4][dk>>5][(dk&31)+32*((s>>3)&1)][s&7]
__global__ __launch_bounds__(256, 3) void k_qkv(
    const _Float16* __restrict__ X,
    const _Float16* __restrict__ Wqh, const _Float16* __restrict__ Wkh,
    const _Float16* __restrict__ Wvh,
    const float* __restrict__ bq, const float* __restrict__ bk,
    const float* __restrict__ bv,
    _Float16* __restrict__ Qo, _Float16* __restrict__ Ko, _Float16* __restrict__ Vo)
{
    __shared__ _Float16 SH[128 * 136];          // staging (As|Bs) + epilogue buffer
    _Float16* As = SH;                          // 128*64
    _Float16* Bs = SH + 128 * 64;               // 128*64
    const int tid = threadIdx.x;
    const int lane = tid & 63, wv = tid >> 6;
    const int wrow = wv >> 1, wcol = wv & 1;
    const int l5 = lane & 31, half = lane >> 5;
    const int which = blockIdx.x >> 3;
    const _Float16* W   = which == 0 ? Wqh : which == 1 ? Wkh : Wvh;
    const float*   bias = which == 0 ? bq  : which == 1 ? bk  : bv;
    const int n0 = (blockIdx.x & 7) * 128;
    const int m0 = blockIdx.y * 128;

    f32x16 acc[2][2];
#pragma unroll
    for (int a = 0; a < 2; ++a)
#pragma unroll
        for (int bb = 0; bb < 2; ++bb)
#pragma unroll
            for (int r = 0; r < 16; ++r) acc[a][bb][r] = 0.f;

#pragma unroll 1
    for (int k0 = 0; k0 < 1024; k0 += 64) {
        __syncthreads();
#pragma unroll
        for (int it = 0; it < 4; ++it) {
            const int wbase = it * 256 + wv * 64;
            const int ci = wbase + lane;
            const int r = ci >> 3;
            const int c8 = (((ci & 7) ^ (r & 7)) * 8);   // XOR-swizzled gather
            gld16(X + (size_t)(m0 + r) * 1024 + k0 + c8, As + wbase * 8);
            gld16(W + (size_t)(n0 + r) * 1024 + k0 + c8, Bs + wbase * 8);
        }
        __syncthreads();
#pragma unroll
        for (int ks = 0; ks < 4; ++ks) {
            f16x8 af[2], bf[2];
#pragma unroll
            for (int mt = 0; mt < 2; ++mt)
                af[mt] = *(const f16x8*)(As + (wrow * 64 + mt * 32 + l5) * 64 +
                                         (((ks * 2 + half) ^ (l5 & 7)) * 8));
#pragma unroll
            for (int nt = 0; nt < 2; ++nt)
                bf[nt] = *(const f16x8*)(Bs + (wcol * 64 + nt * 32 + l5) * 64 +
                                         (((ks * 2 + half) ^ (l5 & 7)) * 8));
#pragma unroll
            for (int mt = 0; mt < 2; ++mt)
#pragma unroll
                for (int nt = 0; nt < 2; ++nt)
                    acc[mt][nt] = MFMA32(af[mt], bf[nt], acc[mt][nt]);
        }
    }

    __syncthreads();   // staging dead; reuse SH for epilogue transpose
    const int b_ = m0 >> 11;
    const int s_base = m0 & 2047;
    // C/D: col = l5 (n/e dim), row = (reg&3)+8*(reg>>2)+4*half (m/s dim)
    if (which == 2) {
        // V: SH[e_l * 136 + m_l] (transposed)
#pragma unroll
        for (int nt = 0; nt < 2; ++nt) {
            const int e_l = wcol * 64 + nt * 32 + l5;
            const float bv_ = bias[n0 + e_l];
#pragma unroll
            for (int mt = 0; mt < 2; ++mt)
#pragma unroll
                for (int g = 0; g < 4; ++g) {
                    const int m_l = wrow * 64 + mt * 32 + 8 * g + 4 * half;
                    f16x4 pk;
#pragma unroll
                    for (int j = 0; j < 4; ++j)
                        pk[j] = (_Float16)(acc[mt][nt][4 * g + j] + bv_);
                    *(f16x4*)(SH + e_l * 136 + m_l) = pk;
                }
        }
        __syncthreads();
#pragma unroll
        for (int p = 0; p < 8; ++p) {
            const int e_l = p * 16 + (tid >> 4);
            const int s8 = (tid & 15) * 8;
            f16x8 vv = *(const f16x8*)(SH + e_l * 136 + s8);
            const int e = n0 + e_l;
            const int h = e >> 6, dk = e & 63;
            const int s0 = s_base + s8;
            // Vp[bh][s0>>4][dk>>5][(dk&31)+32*((s8>>3)&1)][s&7]
            const size_t idx = ((((size_t)(b_ * 16 + h) * 128 + (s0 >> 4)) * 2 +
                                (dk >> 5)) * 64 + (dk & 31) + 32 * ((s8 >> 3) & 1)) * 8;
            *(f16x8*)(Vo + idx) = vv;
        }
    } else {
        const float qs = (which == 0) ? 0.18033688011112042f : 1.0f;  // 0.125*log2e
#pragma unroll
        for (int nt = 0; nt < 2; ++nt) {
            const int e_l = wcol * 64 + nt * 32 + l5;
            const float bv_ = bias[n0 + e_l];
#pragma unroll
            for (int mt = 0; mt < 2; ++mt)
#pragma unroll
                for (int r = 0; r < 16; ++r) {
                    const int m_l = wrow * 64 + mt * 32 + (r & 3) + 8 * (r >> 2) + 4 * half;
                    SH[m_l * 136 + e_l] = (_Float16)((acc[mt][nt][r] + bv_) * qs);
                }
        }
        __syncthreads();
#pragma unroll
        for (int p = 0; p < 8; ++p) {
            const int m_l = p * 16 + (tid >> 4);
            const int c8 = (tid & 15) * 8;
            f16x8 vv = *(const f16x8*)(SH + m_l * 136 + c8);
            const int e = n0 + c8;
            const int h = e >> 6, dk = e & 63;
            const int s = s_base + m_l;
            if (which == 0) {
                *(f16x8*)(Qo + (((size_t)b_ * 16 + h) * 2048 + s) * 64 + dk) = vv;
            } else {
                // Kp[bh][s>>5][dk>>4][(s&31)+32*((dk>>3)&1)][dk&7]
                const size_t idx = ((((size_t)(b_ * 16 + h) * 64 + (s >> 5)) * 4 +
                                    (dk >> 4)) * 64 + (s & 31) + 32 * ((dk >> 3) & 1)) * 8;
                *(f16x8*)(Ko + idx) = vv;
            }
        }
    }
}

// --------------------------- output projection ------------------------------
__global__ __launch_bounds__(256, 4) void k_oproj(
    const _Float16* __restrict__ Oin, const _Float16* __restrict__ Woh,
    const float* __restrict__ bo, float* __restrict__ out)
{
    __shared__ _Float16 As[128 * 64];
    __shared__ _Float16 Bs[64 * 64];
    const int tid = threadIdx.x;
    const int lane = tid & 63, wv = tid >> 6;
    const int quad = lane >> 4, lc = lane & 15;
    const int n0 = blockIdx.x * 64;
    const int m0 = blockIdx.y * 128;

    const f32x4 fzero = {0.f, 0.f, 0.f, 0.f};
    f32x4 acc[2][4];
#pragma unroll
    for (int a = 0; a < 2; ++a)
#pragma unroll
        for (int bb = 0; bb < 4; ++bb) acc[a][bb] = fzero;

#pragma unroll 1
    for (int k0 = 0; k0 < 1024; k0 += 64) {
        __syncthreads();
#pragma unroll
        for (int it = 0; it < 4; ++it) {
            const int ci = it * 256 + tid;
            const int r = ci >> 3;
            const int c8 = (((ci & 7) ^ (r & 7)) * 8);
            gld16(Oin + (size_t)(m0 + r) * 1024 + k0 + c8, As + ci * 8);
        }
#pragma unroll
        for (int it = 0; it < 2; ++it) {
            const int ci = it * 256 + tid;
            const int r = ci >> 3;
            const int c8 = (((ci & 7) ^ (r & 7)) * 8);
            gld16(Woh + (size_t)(n0 + r) * 1024 + k0 + c8, Bs + ci * 8);
        }
        __syncthreads();
#pragma unroll
        for (int ks = 0; ks < 2; ++ks) {
            f16x8 af[2], bf[4];
#pragma unroll
            for (int mt = 0; mt < 2; ++mt)
                af[mt] = *(const f16x8*)(As + (wv * 32 + mt * 16 + lc) * 64 +
                                         (((ks * 4 + quad) ^ (lc & 7)) * 8));
#pragma unroll
            for (int nt = 0; nt < 4; ++nt)
                bf[nt] = *(const f16x8*)(Bs + (nt * 16 + lc) * 64 +
                                         (((ks * 4 + quad) ^ (lc & 7)) * 8));
#pragma unroll
            for (int mt = 0; mt < 2; ++mt)
#pragma unroll
                for (int nt = 0; nt < 4; ++nt)
                    acc[mt][nt] = MFMA16(af[mt], bf[nt], acc[mt][nt]);
        }
    }
#pragma unroll
    for (int nt = 0; nt < 4; ++nt) {
        const int e = n0 + nt * 16 + lc;
        const float bv_ = bo[e];
#pragma unroll
        for (int mt = 0; mt < 2; ++mt)
#pragma unroll
            for (int i = 0; i < 4; ++i) {
                const int m = m0 + wv * 32 + mt * 16 + quad * 4 + i;
                out[(size_t)m * 1024 + e] = acc[mt][nt][i] + bv_;
            }
    }
}

// ----------------------------- flash attention ------------------------------
// 256 thr / 4 waves = 2 q-tiles x 2 k-halves. Wave (qt,kh) computes q-tile
// [blockIdx.y*64 + qt*32, +32) over k-half [kh*1024, +1024) — 32 iters.
// XCD affinity: bh rides blockIdx.x (fastest) -> flattened id = bh + 32*q
// -> XCD = bh%8 for every q-block (32q % 8 == 0). Each XCD L2 then holds
// 4 bh x 512KB = 2MB of K/V (fits 4MB), killing the 8x cross-XCD re-fetch
// (R4: FETCH 70->23MB). No register prefetch — R4 showed +16 regs spills
// (WRITE 10->30MB). K/V read as pre-packed MFMA fragments, no LDS staging,
// no per-iter barriers; raw v_exp_f32 softmax; permlane32_swap P-packing.
__global__ __launch_bounds__(256, 4) void k_attn(
    const _Float16* __restrict__ Q, const _Float16* __restrict__ Kp,
    const _Float16* __restrict__ Vp, const int* __restrict__ mask,
    const int* __restrict__ flag, _Float16* __restrict__ O)
{
    __shared__ float Os[2][32 * 64];   // partial O from kh==1 waves (16 KB)
    __shared__ float Ls[2][32];        // partial l from kh==1 waves

    const int tid = threadIdx.x;
    const int lane = tid & 63, wv = tid >> 6;
    const int l5 = lane & 31, half = lane >> 5;
    const int qt = wv >> 1, kh = wv & 1;
    const int bh = blockIdx.x;               // XCD-affine: bh -> XCD bh%8
    const int b = bh >> 4, h = bh & 15;
    const int qb = blockIdx.y * 64 + qt * 32;

    const _Float16* Qb = Q  + (size_t)bh * 2048 * 64;
    const _Float16* Kb = Kp + (size_t)bh * 131072;   // 64 kblk * 4 kk * 64 * 8
    const _Float16* Vb = Vp + (size_t)bh * 131072;   // 128 kblk * 2 nt * 64 * 8

    // Q fragments (B operand of S^T = K*Q^T): n=q=l5, k(dk)=kk*16+half*8+t
    f16x8 qf[4];
#pragma unroll
    for (int kk = 0; kk < 4; ++kk)
        qf[kk] = *(const f16x8*)(Qb + (size_t)(qb + l5) * 64 + kk * 16 + half * 8);

    const f32x16 fz = {0.f, 0.f, 0.f, 0.f, 0.f, 0.f, 0.f, 0.f,
                       0.f, 0.f, 0.f, 0.f, 0.f, 0.f, 0.f, 0.f};
    const f16x2 one2 = {(_Float16)1.f, (_Float16)1.f};

    f32x16 o[2];
#pragma unroll
    for (int nt = 0; nt < 2; ++nt)
#pragma unroll
        for (int r = 0; r < 16; ++r) o[nt][r] = 0.f;
    float l_i = 0.f;

    const bool has_zero = (*flag != 0);

#pragma unroll 2
    for (int it = 0; it < 32; ++it) {
        const int kb = kh * 32 + it;
        // K fragments: A-operand rows k = kb*32 + l5
        f16x8 kf[4];
#pragma unroll
        for (int kk = 0; kk < 4; ++kk)
            kf[kk] = *(const f16x8*)(Kb + ((size_t)(kb * 4 + kk) * 64 + lane) * 8);
        // V fragments: B-operand, kblk = kb*2+ks, nt = dk half
        f16x8 vf[4];
#pragma unroll
        for (int ks = 0; ks < 2; ++ks)
#pragma unroll
            for (int nt = 0; nt < 2; ++nt)
                vf[ks * 2 + nt] = *(const f16x8*)(Vb +
                    ((size_t)((kb * 2 + ks) * 2 + nt) * 64 + lane) * 8);

        // ---- S^T = K * Q^T ---- (C operand = loop-invariant zero vec)
        __builtin_amdgcn_s_setprio(1);
        f32x16 st = MFMA32(kf[0], qf[0], fz);
        st = MFMA32(kf[1], qf[1], st);
        st = MFMA32(kf[2], qf[2], st);
        st = MFMA32(kf[3], qf[3], st);
        __builtin_amdgcn_s_setprio(0);

        if (has_zero) {  // never taken for all-ones mask
            const int q = qb + l5;
            const int* mr = mask + ((size_t)b * 2048 + q) * 2048 + kb * 32;
            for (int r = 0; r < 16; ++r) {
                const int kk_ = (r & 3) + 8 * (r >> 2) + 4 * half;
                if (mr[kk_] == 0) st[r] = -1e30f;
            }
        }

        // ---- shift-free exp2 softmax: raw v_exp_f32 + pack + fdot2 sum ----
        unsigned u[8];
        float rs = 0.f;
#pragma unroll
        for (int j = 0; j < 8; ++j) {
            const float p0 = EXP2(st[2 * j]);
            const float p1 = EXP2(st[2 * j + 1]);
            u[j] = __builtin_bit_cast(unsigned, __builtin_amdgcn_cvt_pkrtz(p0, p1));
#if __has_builtin(__builtin_amdgcn_fdot2)
            rs = __builtin_amdgcn_fdot2(__builtin_bit_cast(f16x2, u[j]), one2, rs, false);
#else
            rs += p0 + p1;
#endif
        }
        rs += __shfl_xor(rs, 32);   // combine lane-halves (same q)
        l_i += rs;

        // ---- P: C-layout -> A-operand via permlane32_swap half-swap ----
        // swap(A,B): out0 = [A.lo, B.lo], out1 = [A.hi, B.hi]
        u32x2 r02 = __builtin_amdgcn_permlane32_swap(u[0], u[2], false, false);
        u32x2 r13 = __builtin_amdgcn_permlane32_swap(u[1], u[3], false, false);
        u32x2 r46 = __builtin_amdgcn_permlane32_swap(u[4], u[6], false, false);
        u32x2 r57 = __builtin_amdgcn_permlane32_swap(u[5], u[7], false, false);
        i32x4 a0 = { (int)r02[0], (int)r13[0], (int)r02[1], (int)r13[1] };
        i32x4 a1 = { (int)r46[0], (int)r57[0], (int)r46[1], (int)r57[1] };
        f16x8 pa0 = __builtin_bit_cast(f16x8, a0);
        f16x8 pa1 = __builtin_bit_cast(f16x8, a1);

        // ---- O += P * V ----
        __builtin_amdgcn_s_setprio(1);
        o[0] = MFMA32(pa0, vf[0], o[0]);
        o[1] = MFMA32(pa0, vf[1], o[1]);
        o[0] = MFMA32(pa1, vf[2], o[0]);
        o[1] = MFMA32(pa1, vf[3], o[1]);
        __builtin_amdgcn_s_setprio(0);
    }

    // ---- merge k-half partials via LDS (single barrier), normalize, store --
    if (kh == 1) {
        if (half == 0) Ls[qt][l5] = l_i;
#pragma unroll
        for (int nt = 0; nt < 2; ++nt)
#pragma unroll
            for (int r = 0; r < 16; ++r) {
                const int q_loc = (r & 3) + 8 * (r >> 2) + 4 * half;
                Os[qt][q_loc * 64 + nt * 32 + l5] = o[nt][r];
            }
    }
    __syncthreads();
    if (kh == 0) {
        const float linv = 1.f / (l_i + Ls[qt][l5]);   // l indexed by q=l5
#pragma unroll
        for (int r = 0; r < 16; ++r) {
            const int q_loc = (r & 3) + 8 * (r >> 2) + 4 * half;
            const float lv = __shfl(linv, q_loc);
            const int q = qb + q_loc;
            _Float16* orow = O + ((size_t)b * 2048 + q) * 1024 + h * 64;
#pragma unroll
            for (int nt = 0; nt < 2; ++nt) {
                const float val = o[nt][r] + Os[qt][q_loc * 64 + nt * 32 + l5];
                orow[nt * 32 + l5] = (_Float16)(val * lv);
            }
        }
    }
}

// ---------------------------------------------------------------------------
extern "C" void kernel_launch(void* const* d_in, const int* in_sizes, int n_in,
                              void* d_out, int out_size, void* d_ws, size_t ws_size,
                              hipStream_t stream) {
    const float* query = (const float*)d_in[0];
    const int*   mask  = (const int*)d_in[1];
    const float* Wq = (const float*)d_in[2]; const float* bq = (const float*)d_in[3];
    const float* Wk = (const float*)d_in[4]; const float* bk = (const float*)d_in[5];
    const float* Wv = (const float*)d_in[6]; const float* bv = (const float*)d_in[7];
    const float* Wo = (const float*)d_in[8]; const float* bo = (const float*)d_in[9];
    float* out = (float*)d_out;

    char* ws = (char*)d_ws;
    _Float16* Xh  = (_Float16*)(ws);                 // 4096x1024, reused as Oh
    _Float16* Wqh = (_Float16*)(ws + 8388608);
    _Float16* Wkh = (_Float16*)(ws + 10485760);
    _Float16* Wvh = (_Float16*)(ws + 12582912);
    _Float16* Woh = (_Float16*)(ws + 14680064);
    _Float16* Qh  = (_Float16*)(ws + 16777216);
    _Float16* Kh  = (_Float16*)(ws + 25165824);      // packed Kp
    _Float16* Vh  = (_Float16*)(ws + 33554432);      // packed Vp
    _Float16* Oh  = Xh;
    int* flag     = (int*)(ws + 41943040);

    (void)hipMemsetAsync(flag, 0, 4, stream);
    k_pre<<<16384, 256, 0, stream>>>(query, Wq, Wk, Wv, Wo,
                                     Xh, Wqh, Wkh, Wvh, Woh, mask, flag);
    k_qkv<<<dim3(24, 32), 256, 0, stream>>>(Xh, Wqh, Wkh, Wvh, bq, bk, bv, Qh, Kh, Vh);
    k_attn<<<dim3(32, 32), 256, 0, stream>>>(Qh, Kh, Vh, mask, flag, Oh);
    k_oproj<<<dim3(16, 32), 256, 0, stream>>>(Oh, Woh, bo, out);
}

// Round 6
// 208.929 us; speedup vs baseline: 1.2662x; 1.0264x over previous
//
#include <hip/hip_runtime.h>

// ---------------------------------------------------------------------------
// Attention_5978594476296: B=2,S=2048,D=1024,H=16,DK=64
// k_pre -> k_qkv (32x32x16 MFMA bt-GEMM; K,V emitted in MFMA-ready packed
// fragment order; Q pre-scaled) -> k_attn (no-staging flash: packed coalesced
// dwordx4 operand loads, 2 q-tiles x 2 k-halves per block, XCD-affine block
// mapping, deferred-K register pipeline, phase-staggered k order,
// raw v_exp_f32 softmax, permlane32_swap P-packing) -> k_oproj -> f32 out
// R1 lesson: forcing 8 waves/EU spills accumulators (FETCH 69MB->1.1GB).
// R2 lesson: VALUBusy 59% was ~70% libm exp2f expansion + st zero-init.
// R3 lesson: VALU diet verified but wall flat -> latency-bound, not VALU.
// R4 lesson: XCD-affinity works (FETCH 70->23MB). Holding TWO K copies
//   (kfc+kfn, +16 live regs) spills -> WRITE 10->30MB. VGPR_Count only
//   reports arch VGPRs; watch WRITE_SIZE for spill evidence.
// R5 lesson: FETCH 13MB (=ideal) yet wall identical -> NOT BW-bound.
//   43% dead cycles @ 28.5% occupancy (2 blocks/CU, ~190 regs/wave incl.
//   hoisted fz const vec). Limiter = exposed kf latency + lockstep stalls.
// R6: deferred-K reload into SAME regs (pressure-neutral prefetch), fz
//   dropped (per-iter st zero-init, -16 persistent regs -> 3rd block/CU),
//   per-block k-phase stagger (order-invariant partials) to decorrelate
//   co-resident waves' stall windows.
// ---------------------------------------------------------------------------

typedef _Float16 f16x8 __attribute__((ext_vector_type(8)));
typedef _Float16 f16x4 __attribute__((ext_vector_type(4)));
typedef _Float16 f16x2 __attribute__((ext_vector_type(2)));
typedef float    f32x4 __attribute__((ext_vector_type(4)));
typedef float    f32x16 __attribute__((ext_vector_type(16)));
typedef int      i32x4 __attribute__((ext_vector_type(4)));
typedef unsigned u32x2 __attribute__((ext_vector_type(2)));

#define MFMA32(a, b, c) __builtin_amdgcn_mfma_f32_32x32x16_f16(a, b, c, 0, 0, 0)
#define MFMA16(a, b, c) __builtin_amdgcn_mfma_f32_16x16x32_f16(a, b, c, 0, 0, 0)

#if __has_builtin(__builtin_amdgcn_exp2f)
#define EXP2(x) __builtin_amdgcn_exp2f(x)
#else
#define EXP2(x) exp2f(x)
#endif

__device__ __forceinline__ void gld16(const void* g, void* l) {
    __builtin_amdgcn_global_load_lds(
        (const __attribute__((address_space(1))) void*)g,
        (__attribute__((address_space(3))) void*)l, 16, 0, 0);
}

// ---------------- fused preprocessing: 5 convs + mask scan ------------------
__device__ __forceinline__ void conv1k(const float* __restrict__ in,
                                       _Float16* __restrict__ out, int base) {
    const int i = base + threadIdx.x * 4;
    float4 v = *(const float4*)(in + i);
    f16x4 o;
    o.x = (_Float16)v.x; o.y = (_Float16)v.y; o.z = (_Float16)v.z; o.w = (_Float16)v.w;
    *(f16x4*)(out + i) = o;
}

__global__ void k_pre(const float* __restrict__ X, const float* __restrict__ Wq,
                      const float* __restrict__ Wk, const float* __restrict__ Wv,
                      const float* __restrict__ Wo,
                      _Float16* __restrict__ Xh, _Float16* __restrict__ Wqh,
                      _Float16* __restrict__ Wkh, _Float16* __restrict__ Wvh,
                      _Float16* __restrict__ Woh,
                      const int* __restrict__ mask, int* __restrict__ flag) {
    const int bid = blockIdx.x;
    if (bid < 4096)      conv1k(X,  Xh,  bid * 1024);
    else if (bid < 5120) conv1k(Wq, Wqh, (bid - 4096) * 1024);
    else if (bid < 6144) conv1k(Wk, Wkh, (bid - 5120) * 1024);
    else if (bid < 7168) conv1k(Wv, Wvh, (bid - 6144) * 1024);
    else if (bid < 8192) conv1k(Wo, Woh, (bid - 7168) * 1024);
    else {
        const int i = (bid - 8192) * 1024 + threadIdx.x * 4;
        int4 v = *(const int4*)(mask + i);
        if ((v.x == 0) | (v.y == 0) | (v.z == 0) | (v.w == 0)) atomicOr(flag, 1);
    }
}

// --------------------- fused QKV projection (bt-GEMM) -----------------------
// Q out: (B,H,S,DK), pre-scaled by 0.125*log2e.
// K out: packed A-frag order Kp[bh][s>>5][dk>>4][(s&31)+32*((dk>>3)&1)][dk&7]
// V out: packed B-frag order Vp[bh][s>>4][dk>>5][(dk&31)+32*((s>>3)&1)][s&7]
__global__ __launch_bounds__(256, 3) void k_qkv(
    const _Float16* __restrict__ X,
    const _Float16* __restrict__ Wqh, const _Float16* __restrict__ Wkh,
    const _Float16* __restrict__ Wvh,
    const float* __restrict__ bq, const float* __restrict__ bk,
    const float* __restrict__ bv,
    _Float16* __restrict__ Qo, _Float16* __restrict__ Ko, _Float16* __restrict__ Vo)
{
    __shared__ _Float16 SH[128 * 136];          // staging (As|Bs) + epilogue buffer
    _Float16* As = SH;                          // 128*64
    _Float16* Bs = SH + 128 * 64;               // 128*64
    const int tid = threadIdx.x;
    const int lane = tid & 63, wv = tid >> 6;
    const int wrow = wv >> 1, wcol = wv & 1;
    const int l5 = lane & 31, half = lane >> 5;
    const int which = blockIdx.x >> 3;
    const _Float16* W   = which == 0 ? Wqh : which == 1 ? Wkh : Wvh;
    const float*   bias = which == 0 ? bq  : which == 1 ? bk  : bv;
    const int n0 = (blockIdx.x & 7) * 128;
    const int m0 = blockIdx.y * 128;

    f32x16 acc[2][2];
#pragma unroll
    for (int a = 0; a < 2; ++a)
#pragma unroll
        for (int bb = 0; bb < 2; ++bb)
#pragma unroll
            for (int r = 0; r < 16; ++r) acc[a][bb][r] = 0.f;

#pragma unroll 1
    for (int k0 = 0; k0 < 1024; k0 += 64) {
        __syncthreads();
#pragma unroll
        for (int it = 0; it < 4; ++it) {
            const int wbase = it * 256 + wv * 64;
            const int ci = wbase + lane;
            const int r = ci >> 3;
            const int c8 = (((ci & 7) ^ (r & 7)) * 8);   // XOR-swizzled gather
            gld16(X + (size_t)(m0 + r) * 1024 + k0 + c8, As + wbase * 8);
            gld16(W + (size_t)(n0 + r) * 1024 + k0 + c8, Bs + wbase * 8);
        }
        __syncthreads();
#pragma unroll
        for (int ks = 0; ks < 4; ++ks) {
            f16x8 af[2], bf[2];
#pragma unroll
            for (int mt = 0; mt < 2; ++mt)
                af[mt] = *(const f16x8*)(As + (wrow * 64 + mt * 32 + l5) * 64 +
                                         (((ks * 2 + half) ^ (l5 & 7)) * 8));
#pragma unroll
            for (int nt = 0; nt < 2; ++nt)
                bf[nt] = *(const f16x8*)(Bs + (wcol * 64 + nt * 32 + l5) * 64 +
                                         (((ks * 2 + half) ^ (l5 & 7)) * 8));
#pragma unroll
            for (int mt = 0; mt < 2; ++mt)
#pragma unroll
                for (int nt = 0; nt < 2; ++nt)
                    acc[mt][nt] = MFMA32(af[mt], bf[nt], acc[mt][nt]);
        }
    }

    __syncthreads();   // staging dead; reuse SH for epilogue transpose
    const int b_ = m0 >> 11;
    const int s_base = m0 & 2047;
    // C/D: col = l5 (n/e dim), row = (reg&3)+8*(reg>>2)+4*half (m/s dim)
    if (which == 2) {
        // V: SH[e_l * 136 + m_l] (transposed)
#pragma unroll
        for (int nt = 0; nt < 2; ++nt) {
            const int e_l = wcol * 64 + nt * 32 + l5;
            const float bv_ = bias[n0 + e_l];
#pragma unroll
            for (int mt = 0; mt < 2; ++mt)
#pragma unroll
                for (int g = 0; g < 4; ++g) {
                    const int m_l = wrow * 64 + mt * 32 + 8 * g + 4 * half;
                    f16x4 pk;
#pragma unroll
                    for (int j = 0; j < 4; ++j)
                        pk[j] = (_Float16)(acc[mt][nt][4 * g + j] + bv_);
                    *(f16x4*)(SH + e_l * 136 + m_l) = pk;
                }
        }
        __syncthreads();
#pragma unroll
        for (int p = 0; p < 8; ++p) {
            const int e_l = p * 16 + (tid >> 4);
            const int s8 = (tid & 15) * 8;
            f16x8 vv = *(const f16x8*)(SH + e_l * 136 + s8);
            const int e = n0 + e_l;
            const int h = e >> 6, dk = e & 63;
            const int s0 = s_base + s8;
            // Vp[bh][s0>>4][dk>>5][(dk&31)+32*((s8>>3)&1)][s&7]
            const size_t idx = ((((size_t)(b_ * 16 + h) * 128 + (s0 >> 4)) * 2 +
                                (dk >> 5)) * 64 + (dk & 31) + 32 * ((s8 >> 3) & 1)) * 8;
            *(f16x8*)(Vo + idx) = vv;
        }
    } else {
        const float qs = (which == 0) ? 0.18033688011112042f : 1.0f;  // 0.125*log2e
#pragma unroll
        for (int nt = 0; nt < 2; ++nt) {
            const int e_l = wcol * 64 + nt * 32 + l5;
            const float bv_ = bias[n0 + e_l];
#pragma unroll
            for (int mt = 0; mt < 2; ++mt)
#pragma unroll
                for (int r = 0; r < 16; ++r) {
                    const int m_l = wrow * 64 + mt * 32 + (r & 3) + 8 * (r >> 2) + 4 * half;
                    SH[m_l * 136 + e_l] = (_Float16)((acc[mt][nt][r] + bv_) * qs);
                }
        }
        __syncthreads();
#pragma unroll
        for (int p = 0; p < 8; ++p) {
            const int m_l = p * 16 + (tid >> 4);
            const int c8 = (tid & 15) * 8;
            f16x8 vv = *(const f16x8*)(SH + m_l * 136 + c8);
            const int e = n0 + c8;
            const int h = e >> 6, dk = e & 63;
            const int s = s_base + m_l;
            if (which == 0) {
                *(f16x8*)(Qo + (((size_t)b_ * 16 + h) * 2048 + s) * 64 + dk) = vv;
            } else {
                // Kp[bh][s>>5][dk>>4][(s&31)+32*((dk>>3)&1)][dk&7]
                const size_t idx = ((((size_t)(b_ * 16 + h) * 64 + (s >> 5)) * 4 +
                                    (dk >> 4)) * 64 + (s & 31) + 32 * ((dk >> 3) & 1)) * 8;
                *(f16x8*)(Ko + idx) = vv;
            }
        }
    }
}

// --------------------------- output projection ------------------------------
__global__ __launch_bounds__(256, 4) void k_oproj(
    const _Float16* __restrict__ Oin, const _Float16* __restrict__ Woh,
    const float* __restrict__ bo, float* __restrict__ out)
{
    __shared__ _Float16 As[128 * 64];
    __shared__ _Float16 Bs[64 * 64];
    const int tid = threadIdx.x;
    const int lane = tid & 63, wv = tid >> 6;
    const int quad = lane >> 4, lc = lane & 15;
    const int n0 = blockIdx.x * 64;
    const int m0 = blockIdx.y * 128;

    const f32x4 fzero = {0.f, 0.f, 0.f, 0.f};
    f32x4 acc[2][4];
#pragma unroll
    for (int a = 0; a < 2; ++a)
#pragma unroll
        for (int bb = 0; bb < 4; ++bb) acc[a][bb] = fzero;

#pragma unroll 1
    for (int k0 = 0; k0 < 1024; k0 += 64) {
        __syncthreads();
#pragma unroll
        for (int it = 0; it < 4; ++it) {
            const int ci = it * 256 + tid;
            const int r = ci >> 3;
            const int c8 = (((ci & 7) ^ (r & 7)) * 8);
            gld16(Oin + (size_t)(m0 + r) * 1024 + k0 + c8, As + ci * 8);
        }
#pragma unroll
        for (int it = 0; it < 2; ++it) {
            const int ci = it * 256 + tid;
            const int r = ci >> 3;
            const int c8 = (((ci & 7) ^ (r & 7)) * 8);
            gld16(Woh + (size_t)(n0 + r) * 1024 + k0 + c8, Bs + ci * 8);
        }
        __syncthreads();
#pragma unroll
        for (int ks = 0; ks < 2; ++ks) {
            f16x8 af[2], bf[4];
#pragma unroll
            for (int mt = 0; mt < 2; ++mt)
                af[mt] = *(const f16x8*)(As + (wv * 32 + mt * 16 + lc) * 64 +
                                         (((ks * 4 + quad) ^ (lc & 7)) * 8));
#pragma unroll
            for (int nt = 0; nt < 4; ++nt)
                bf[nt] = *(const f16x8*)(Bs + (nt * 16 + lc) * 64 +
                                         (((ks * 4 + quad) ^ (lc & 7)) * 8));
#pragma unroll
            for (int mt = 0; mt < 2; ++mt)
#pragma unroll
                for (int nt = 0; nt < 4; ++nt)
                    acc[mt][nt] = MFMA16(af[mt], bf[nt], acc[mt][nt]);
        }
    }
#pragma unroll
    for (int nt = 0; nt < 4; ++nt) {
        const int e = n0 + nt * 16 + lc;
        const float bv_ = bo[e];
#pragma unroll
        for (int mt = 0; mt < 2; ++mt)
#pragma unroll
            for (int i = 0; i < 4; ++i) {
                const int m = m0 + wv * 32 + mt * 16 + quad * 4 + i;
                out[(size_t)m * 1024 + e] = acc[mt][nt][i] + bv_;
            }
    }
}

// ----------------------------- flash attention ------------------------------
// 256 thr / 4 waves = 2 q-tiles x 2 k-halves. Wave (qt,kh) computes q-tile
// [blockIdx.y*64 + qt*32, +32) over k-half [kh*1024, +1024) — 32 iters.
// XCD affinity: bh rides blockIdx.x (R4/R5: FETCH 70->13MB, L2-resident K/V).
// Deferred-K pipeline: kf for iter i+1 loaded right AFTER QK of iter i into
// the SAME 16 regs (dead there) — latency covered by softmax+PV+vf-issue,
// zero extra registers (R4's dual-copy version spilled).
// Phase stagger: per-block k-start offset (partials are order-invariant
// under shift-free softmax) so co-resident blocks stall in different windows.
// st zero-init per iter (no persistent fz vec) to fit a 3rd block/CU.
__global__ __launch_bounds__(256, 4) void k_attn(
    const _Float16* __restrict__ Q, const _Float16* __restrict__ Kp,
    const _Float16* __restrict__ Vp, const int* __restrict__ mask,
    const int* __restrict__ flag, _Float16* __restrict__ O)
{
    __shared__ float Os[2][32 * 64];   // partial O from kh==1 waves (16 KB)
    __shared__ float Ls[2][32];        // partial l from kh==1 waves

    const int tid = threadIdx.x;
    const int lane = tid & 63, wv = tid >> 6;
    const int l5 = lane & 31, half = lane >> 5;
    const int qt = wv >> 1, kh = wv & 1;
    const int bh = blockIdx.x;               // XCD-affine: bh -> XCD bh%8
    const int b = bh >> 4, h = bh & 15;
    const int qb = blockIdx.y * 64 + qt * 32;
    const int phase = (bh & 3) * 8;          // per-block k-order rotation

    const _Float16* Qb = Q  + (size_t)bh * 2048 * 64;
    const _Float16* Kb = Kp + (size_t)bh * 131072;   // 64 kblk * 4 kk * 64 * 8
    const _Float16* Vb = Vp + (size_t)bh * 131072;   // 128 kblk * 2 nt * 64 * 8

    // Q fragments (B operand of S^T = K*Q^T): n=q=l5, k(dk)=kk*16+half*8+t
    f16x8 qf[4];
#pragma unroll
    for (int kk = 0; kk < 4; ++kk)
        qf[kk] = *(const f16x8*)(Qb + (size_t)(qb + l5) * 64 + kk * 16 + half * 8);

    const f16x2 one2 = {(_Float16)1.f, (_Float16)1.f};

    f32x16 o[2];
#pragma unroll
    for (int nt = 0; nt < 2; ++nt)
#pragma unroll
        for (int r = 0; r < 16; ++r) o[nt][r] = 0.f;
    float l_i = 0.f;

    const bool has_zero = (*flag != 0);

    // ---- prologue: K fragments for first (rotated) iteration ----
    f16x8 kf[4];
    {
        const int kb0 = kh * 32 + phase;
#pragma unroll
        for (int kk = 0; kk < 4; ++kk)
            kf[kk] = *(const f16x8*)(Kb + ((size_t)(kb0 * 4 + kk) * 64 + lane) * 8);
    }

#pragma unroll 2
    for (int it = 0; it < 32; ++it) {
        const int kb = kh * 32 + ((it + phase) & 31);
        // V fragments for current iter: consumed after softmax (long cover)
        f16x8 vf[4];
#pragma unroll
        for (int ks = 0; ks < 2; ++ks)
#pragma unroll
            for (int nt = 0; nt < 2; ++nt)
                vf[ks * 2 + nt] = *(const f16x8*)(Vb +
                    ((size_t)((kb * 2 + ks) * 2 + nt) * 64 + lane) * 8);

        // ---- S^T = K * Q^T ---- (kf loaded one iteration ago)
        f32x16 st;
#pragma unroll
        for (int r = 0; r < 16; ++r) st[r] = 0.f;
        __builtin_amdgcn_s_setprio(1);
        st = MFMA32(kf[0], qf[0], st);
        st = MFMA32(kf[1], qf[1], st);
        st = MFMA32(kf[2], qf[2], st);
        st = MFMA32(kf[3], qf[3], st);
        __builtin_amdgcn_s_setprio(0);

        // ---- deferred K reload for next iter (kf dead; same regs) ----
        {
            const int nkb = kh * 32 + ((it + 1 + phase) & 31);
#pragma unroll
            for (int kk = 0; kk < 4; ++kk)
                kf[kk] = *(const f16x8*)(Kb + ((size_t)(nkb * 4 + kk) * 64 + lane) * 8);
        }

        if (has_zero) {  // never taken for all-ones mask
            const int q = qb + l5;
            const int* mr = mask + ((size_t)b * 2048 + q) * 2048 + kb * 32;
            for (int r = 0; r < 16; ++r) {
                const int kk_ = (r & 3) + 8 * (r >> 2) + 4 * half;
                if (mr[kk_] == 0) st[r] = -1e30f;
            }
        }

        // ---- shift-free exp2 softmax: raw v_exp_f32 + pack + fdot2 sum ----
        unsigned u[8];
        float rs = 0.f;
#pragma unroll
        for (int j = 0; j < 8; ++j) {
            const float p0 = EXP2(st[2 * j]);
            const float p1 = EXP2(st[2 * j + 1]);
            u[j] = __builtin_bit_cast(unsigned, __builtin_amdgcn_cvt_pkrtz(p0, p1));
#if __has_builtin(__builtin_amdgcn_fdot2)
            rs = __builtin_amdgcn_fdot2(__builtin_bit_cast(f16x2, u[j]), one2, rs, false);
#else
            rs += p0 + p1;
#endif
        }
        rs += __shfl_xor(rs, 32);   // combine lane-halves (same q)
        l_i += rs;

        // ---- P: C-layout -> A-operand via permlane32_swap half-swap ----
        // swap(A,B): out0 = [A.lo, B.lo], out1 = [A.hi, B.hi]
        u32x2 r02 = __builtin_amdgcn_permlane32_swap(u[0], u[2], false, false);
        u32x2 r13 = __builtin_amdgcn_permlane32_swap(u[1], u[3], false, false);
        u32x2 r46 = __builtin_amdgcn_permlane32_swap(u[4], u[6], false, false);
        u32x2 r57 = __builtin_amdgcn_permlane32_swap(u[5], u[7], false, false);
        i32x4 a0 = { (int)r02[0], (int)r13[0], (int)r02[1], (int)r13[1] };
        i32x4 a1 = { (int)r46[0], (int)r57[0], (int)r46[1], (int)r57[1] };
        f16x8 pa0 = __builtin_bit_cast(f16x8, a0);
        f16x8 pa1 = __builtin_bit_cast(f16x8, a1);

        // ---- O += P * V ----
        __builtin_amdgcn_s_setprio(1);
        o[0] = MFMA32(pa0, vf[0], o[0]);
        o[1] = MFMA32(pa0, vf[1], o[1]);
        o[0] = MFMA32(pa1, vf[2], o[0]);
        o[1] = MFMA32(pa1, vf[3], o[1]);
        __builtin_amdgcn_s_setprio(0);
    }

    // ---- merge k-half partials via LDS (single barrier), normalize, store --
    if (kh == 1) {
        if (half == 0) Ls[qt][l5] = l_i;
#pragma unroll
        for (int nt = 0; nt < 2; ++nt)
#pragma unroll
            for (int r = 0; r < 16; ++r) {
                const int q_loc = (r & 3) + 8 * (r >> 2) + 4 * half;
                Os[qt][q_loc * 64 + nt * 32 + l5] = o[nt][r];
            }
    }
    __syncthreads();
    if (kh == 0) {
        const float linv = 1.f / (l_i + Ls[qt][l5]);   // l indexed by q=l5
#pragma unroll
        for (int r = 0; r < 16; ++r) {
            const int q_loc = (r & 3) + 8 * (r >> 2) + 4 * half;
            const float lv = __shfl(linv, q_loc);
            const int q = qb + q_loc;
            _Float16* orow = O + ((size_t)b * 2048 + q) * 1024 + h * 64;
#pragma unroll
            for (int nt = 0; nt < 2; ++nt) {
                const float val = o[nt][r] + Os[qt][q_loc * 64 + nt * 32 + l5];
                orow[nt * 32 + l5] = (_Float16)(val * lv);
            }
        }
    }
}

// ---------------------------------------------------------------------------
extern "C" void kernel_launch(void* const* d_in, const int* in_sizes, int n_in,
                              void* d_out, int out_size, void* d_ws, size_t ws_size,
                              hipStream_t stream) {
    const float* query = (const float*)d_in[0];
    const int*   mask  = (const int*)d_in[1];
    const float* Wq = (const float*)d_in[2]; const float* bq = (const float*)d_in[3];
    const float* Wk = (const float*)d_in[4]; const float* bk = (const float*)d_in[5];
    const float* Wv = (const float*)d_in[6]; const float* bv = (const float*)d_in[7];
    const float* Wo = (const float*)d_in[8]; const float* bo = (const float*)d_in[9];
    float* out = (float*)d_out;

    char* ws = (char*)d_ws;
    _Float16* Xh  = (_Float16*)(ws);                 // 4096x1024, reused as Oh
    _Float16* Wqh = (_Float16*)(ws + 8388608);
    _Float16* Wkh = (_Float16*)(ws + 10485760);
    _Float16* Wvh = (_Float16*)(ws + 12582912);
    _Float16* Woh = (_Float16*)(ws + 14680064);
    _Float16* Qh  = (_Float16*)(ws + 16777216);
    _Float16* Kh  = (_Float16*)(ws + 25165824);      // packed Kp
    _Float16* Vh  = (_Float16*)(ws + 33554432);      // packed Vp
    _Float16* Oh  = Xh;
    int* flag     = (int*)(ws + 41943040);

    (void)hipMemsetAsync(flag, 0, 4, stream);
    k_pre<<<16384, 256, 0, stream>>>(query, Wq, Wk, Wv, Wo,
                                     Xh, Wqh, Wkh, Wvh, Woh, mask, flag);
    k_qkv<<<dim3(24, 32), 256, 0, stream>>>(Xh, Wqh, Wkh, Wvh, bq, bk, bv, Qh, Kh, Vh);
    k_attn<<<dim3(32, 32), 256, 0, stream>>>(Qh, Kh, Vh, mask, flag, Oh);
    k_oproj<<<dim3(16, 32), 256, 0, stream>>>(Oh, Woh, bo, out);
}

// Round 7
// 205.731 us; speedup vs baseline: 1.2858x; 1.0155x over previous
//
#include <hip/hip_runtime.h>

// ---------------------------------------------------------------------------
// Attention_5978594476296: B=2,S=2048,D=1024,H=16,DK=64
// k_pre -> k_qkv (32x32x16 MFMA bt-GEMM; K,V emitted in MFMA-ready packed
// fragment order; Q pre-scaled) -> k_attn (LDS-shared flash: 4 q-tiles x
// full-k per block, double-buffered K/V staging via global_load_lds, one
// barrier/iter, no partial merge; XCD-affine bh mapping; raw v_exp_f32
// softmax; permlane32_swap P-packing) -> k_oproj -> f32 out
// R1: forcing 8 waves/EU spills accumulators (FETCH 69MB->1.1GB).
// R2: VALUBusy 59% was ~70% libm exp2f expansion + st zero-init.
// R3: VALU diet verified but wall flat -> latency-bound, not VALU.
// R4: XCD-affinity works (FETCH 70->23MB). Dual K copies (+16 live regs)
//     spill -> WRITE 10->30MB. Watch WRITE_SIZE, not VGPR_Count, for spills.
// R5: FETCH 13MB (=ideal) yet wall flat -> NOT HBM-bound.
// R6: deferred-K +12%. Remaining 35% dead = L2 BW: private per-wave K/V
//     streams = 4MB/CU/pass ~= 20 TB/s = 58% of L2 ceiling. Fix = share K/V
//     across waves via LDS (4x traffic cut) -- this revision.
// ---------------------------------------------------------------------------

typedef _Float16 f16x8 __attribute__((ext_vector_type(8)));
typedef _Float16 f16x4 __attribute__((ext_vector_type(4)));
typedef _Float16 f16x2 __attribute__((ext_vector_type(2)));
typedef float    f32x4 __attribute__((ext_vector_type(4)));
typedef float    f32x16 __attribute__((ext_vector_type(16)));
typedef int      i32x4 __attribute__((ext_vector_type(4)));
typedef unsigned u32x2 __attribute__((ext_vector_type(2)));

#define MFMA32(a, b, c) __builtin_amdgcn_mfma_f32_32x32x16_f16(a, b, c, 0, 0, 0)
#define MFMA16(a, b, c) __builtin_amdgcn_mfma_f32_16x16x32_f16(a, b, c, 0, 0, 0)

#if __has_builtin(__builtin_amdgcn_exp2f)
#define EXP2(x) __builtin_amdgcn_exp2f(x)
#else
#define EXP2(x) exp2f(x)
#endif

__device__ __forceinline__ void gld16(const void* g, void* l) {
    __builtin_amdgcn_global_load_lds(
        (const __attribute__((address_space(1))) void*)g,
        (__attribute__((address_space(3))) void*)l, 16, 0, 0);
}

// ---------------- fused preprocessing: 5 convs + mask scan ------------------
__device__ __forceinline__ void conv1k(const float* __restrict__ in,
                                       _Float16* __restrict__ out, int base) {
    const int i = base + threadIdx.x * 4;
    float4 v = *(const float4*)(in + i);
    f16x4 o;
    o.x = (_Float16)v.x; o.y = (_Float16)v.y; o.z = (_Float16)v.z; o.w = (_Float16)v.w;
    *(f16x4*)(out + i) = o;
}

__global__ void k_pre(const float* __restrict__ X, const float* __restrict__ Wq,
                      const float* __restrict__ Wk, const float* __restrict__ Wv,
                      const float* __restrict__ Wo,
                      _Float16* __restrict__ Xh, _Float16* __restrict__ Wqh,
                      _Float16* __restrict__ Wkh, _Float16* __restrict__ Wvh,
                      _Float16* __restrict__ Woh,
                      const int* __restrict__ mask, int* __restrict__ flag) {
    const int bid = blockIdx.x;
    if (bid < 4096)      conv1k(X,  Xh,  bid * 1024);
    else if (bid < 5120) conv1k(Wq, Wqh, (bid - 4096) * 1024);
    else if (bid < 6144) conv1k(Wk, Wkh, (bid - 5120) * 1024);
    else if (bid < 7168) conv1k(Wv, Wvh, (bid - 6144) * 1024);
    else if (bid < 8192) conv1k(Wo, Woh, (bid - 7168) * 1024);
    else {
        const int i = (bid - 8192) * 1024 + threadIdx.x * 4;
        int4 v = *(const int4*)(mask + i);
        if ((v.x == 0) | (v.y == 0) | (v.z == 0) | (v.w == 0)) atomicOr(flag, 1);
    }
}

// --------------------- fused QKV projection (bt-GEMM) -----------------------
// Q out: (B,H,S,DK), pre-scaled by 0.125*log2e.
// K out: packed A-frag order Kp[bh][s>>5][dk>>4][(s&31)+32*((dk>>3)&1)][dk&7]
// V out: packed B-frag order Vp[bh][s>>4][dk>>5][(dk&31)+32*((s>>3)&1)][s&7]
__global__ __launch_bounds__(256, 3) void k_qkv(
    const _Float16* __restrict__ X,
    const _Float16* __restrict__ Wqh, const _Float16* __restrict__ Wkh,
    const _Float16* __restrict__ Wvh,
    const float* __restrict__ bq, const float* __restrict__ bk,
    const float* __restrict__ bv,
    _Float16* __restrict__ Qo, _Float16* __restrict__ Ko, _Float16* __restrict__ Vo)
{
    __shared__ _Float16 SH[128 * 136];          // staging (As|Bs) + epilogue buffer
    _Float16* As = SH;                          // 128*64
    _Float16* Bs = SH + 128 * 64;               // 128*64
    const int tid = threadIdx.x;
    const int lane = tid & 63, wv = tid >> 6;
    const int wrow = wv >> 1, wcol = wv & 1;
    const int l5 = lane & 31, half = lane >> 5;
    const int which = blockIdx.x >> 3;
    const _Float16* W   = which == 0 ? Wqh : which == 1 ? Wkh : Wvh;
    const float*   bias = which == 0 ? bq  : which == 1 ? bk  : bv;
    const int n0 = (blockIdx.x & 7) * 128;
    const int m0 = blockIdx.y * 128;

    f32x16 acc[2][2];
#pragma unroll
    for (int a = 0; a < 2; ++a)
#pragma unroll
        for (int bb = 0; bb < 2; ++bb)
#pragma unroll
            for (int r = 0; r < 16; ++r) acc[a][bb][r] = 0.f;

#pragma unroll 1
    for (int k0 = 0; k0 < 1024; k0 += 64) {
        __syncthreads();
#pragma unroll
        for (int it = 0; it < 4; ++it) {
            const int wbase = it * 256 + wv * 64;
            const int ci = wbase + lane;
            const int r = ci >> 3;
            const int c8 = (((ci & 7) ^ (r & 7)) * 8);   // XOR-swizzled gather
            gld16(X + (size_t)(m0 + r) * 1024 + k0 + c8, As + wbase * 8);
            gld16(W + (size_t)(n0 + r) * 1024 + k0 + c8, Bs + wbase * 8);
        }
        __syncthreads();
#pragma unroll
        for (int ks = 0; ks < 4; ++ks) {
            f16x8 af[2], bf[2];
#pragma unroll
            for (int mt = 0; mt < 2; ++mt)
                af[mt] = *(const f16x8*)(As + (wrow * 64 + mt * 32 + l5) * 64 +
                                         (((ks * 2 + half) ^ (l5 & 7)) * 8));
#pragma unroll
            for (int nt = 0; nt < 2; ++nt)
                bf[nt] = *(const f16x8*)(Bs + (wcol * 64 + nt * 32 + l5) * 64 +
                                         (((ks * 2 + half) ^ (l5 & 7)) * 8));
#pragma unroll
            for (int mt = 0; mt < 2; ++mt)
#pragma unroll
                for (int nt = 0; nt < 2; ++nt)
                    acc[mt][nt] = MFMA32(af[mt], bf[nt], acc[mt][nt]);
        }
    }

    __syncthreads();   // staging dead; reuse SH for epilogue transpose
    const int b_ = m0 >> 11;
    const int s_base = m0 & 2047;
    // C/D: col = l5 (n/e dim), row = (reg&3)+8*(reg>>2)+4*half (m/s dim)
    if (which == 2) {
        // V: SH[e_l * 136 + m_l] (transposed)
#pragma unroll
        for (int nt = 0; nt < 2; ++nt) {
            const int e_l = wcol * 64 + nt * 32 + l5;
            const float bv_ = bias[n0 + e_l];
#pragma unroll
            for (int mt = 0; mt < 2; ++mt)
#pragma unroll
                for (int g = 0; g < 4; ++g) {
                    const int m_l = wrow * 64 + mt * 32 + 8 * g + 4 * half;
                    f16x4 pk;
#pragma unroll
                    for (int j = 0; j < 4; ++j)
                        pk[j] = (_Float16)(acc[mt][nt][4 * g + j] + bv_);
                    *(f16x4*)(SH + e_l * 136 + m_l) = pk;
                }
        }
        __syncthreads();
#pragma unroll
        for (int p = 0; p < 8; ++p) {
            const int e_l = p * 16 + (tid >> 4);
            const int s8 = (tid & 15) * 8;
            f16x8 vv = *(const f16x8*)(SH + e_l * 136 + s8);
            const int e = n0 + e_l;
            const int h = e >> 6, dk = e & 63;
            const int s0 = s_base + s8;
            // Vp[bh][s0>>4][dk>>5][(dk&31)+32*((s8>>3)&1)][s&7]
            const size_t idx = ((((size_t)(b_ * 16 + h) * 128 + (s0 >> 4)) * 2 +
                                (dk >> 5)) * 64 + (dk & 31) + 32 * ((s8 >> 3) & 1)) * 8;
            *(f16x8*)(Vo + idx) = vv;
        }
    } else {
        const float qs = (which == 0) ? 0.18033688011112042f : 1.0f;  // 0.125*log2e
#pragma unroll
        for (int nt = 0; nt < 2; ++nt) {
            const int e_l = wcol * 64 + nt * 32 + l5;
            const float bv_ = bias[n0 + e_l];
#pragma unroll
            for (int mt = 0; mt < 2; ++mt)
#pragma unroll
                for (int r = 0; r < 16; ++r) {
                    const int m_l = wrow * 64 + mt * 32 + (r & 3) + 8 * (r >> 2) + 4 * half;
                    SH[m_l * 136 + e_l] = (_Float16)((acc[mt][nt][r] + bv_) * qs);
                }
        }
        __syncthreads();
#pragma unroll
        for (int p = 0; p < 8; ++p) {
            const int m_l = p * 16 + (tid >> 4);
            const int c8 = (tid & 15) * 8;
            f16x8 vv = *(const f16x8*)(SH + m_l * 136 + c8);
            const int e = n0 + c8;
            const int h = e >> 6, dk = e & 63;
            const int s = s_base + m_l;
            if (which == 0) {
                *(f16x8*)(Qo + (((size_t)b_ * 16 + h) * 2048 + s) * 64 + dk) = vv;
            } else {
                // Kp[bh][s>>5][dk>>4][(s&31)+32*((dk>>3)&1)][dk&7]
                const size_t idx = ((((size_t)(b_ * 16 + h) * 64 + (s >> 5)) * 4 +
                                    (dk >> 4)) * 64 + (s & 31) + 32 * ((dk >> 3) & 1)) * 8;
                *(f16x8*)(Ko + idx) = vv;
            }
        }
    }
}

// --------------------------- output projection ------------------------------
__global__ __launch_bounds__(256, 4) void k_oproj(
    const _Float16* __restrict__ Oin, const _Float16* __restrict__ Woh,
    const float* __restrict__ bo, float* __restrict__ out)
{
    __shared__ _Float16 As[128 * 64];
    __shared__ _Float16 Bs[64 * 64];
    const int tid = threadIdx.x;
    const int lane = tid & 63, wv = tid >> 6;
    const int quad = lane >> 4, lc = lane & 15;
    const int n0 = blockIdx.x * 64;
    const int m0 = blockIdx.y * 128;

    const f32x4 fzero = {0.f, 0.f, 0.f, 0.f};
    f32x4 acc[2][4];
#pragma unroll
    for (int a = 0; a < 2; ++a)
#pragma unroll
        for (int bb = 0; bb < 4; ++bb) acc[a][bb] = fzero;

#pragma unroll 1
    for (int k0 = 0; k0 < 1024; k0 += 64) {
        __syncthreads();
#pragma unroll
        for (int it = 0; it < 4; ++it) {
            const int ci = it * 256 + tid;
            const int r = ci >> 3;
            const int c8 = (((ci & 7) ^ (r & 7)) * 8);
            gld16(Oin + (size_t)(m0 + r) * 1024 + k0 + c8, As + ci * 8);
        }
#pragma unroll
        for (int it = 0; it < 2; ++it) {
            const int ci = it * 256 + tid;
            const int r = ci >> 3;
            const int c8 = (((ci & 7) ^ (r & 7)) * 8);
            gld16(Woh + (size_t)(n0 + r) * 1024 + k0 + c8, Bs + ci * 8);
        }
        __syncthreads();
#pragma unroll
        for (int ks = 0; ks < 2; ++ks) {
            f16x8 af[2], bf[4];
#pragma unroll
            for (int mt = 0; mt < 2; ++mt)
                af[mt] = *(const f16x8*)(As + (wv * 32 + mt * 16 + lc) * 64 +
                                         (((ks * 4 + quad) ^ (lc & 7)) * 8));
#pragma unroll
            for (int nt = 0; nt < 4; ++nt)
                bf[nt] = *(const f16x8*)(Bs + (nt * 16 + lc) * 64 +
                                         (((ks * 4 + quad) ^ (lc & 7)) * 8));
#pragma unroll
            for (int mt = 0; mt < 2; ++mt)
#pragma unroll
                for (int nt = 0; nt < 4; ++nt)
                    acc[mt][nt] = MFMA16(af[mt], bf[nt], acc[mt][nt]);
        }
    }
#pragma unroll
    for (int nt = 0; nt < 4; ++nt) {
        const int e = n0 + nt * 16 + lc;
        const float bv_ = bo[e];
#pragma unroll
        for (int mt = 0; mt < 2; ++mt)
#pragma unroll
            for (int i = 0; i < 4; ++i) {
                const int m = m0 + wv * 32 + mt * 16 + quad * 4 + i;
                out[(size_t)m * 1024 + e] = acc[mt][nt][i] + bv_;
            }
    }
}

// ----------------------------- flash attention ------------------------------
// 256 thr / 4 waves = 4 q-tiles x full k. Wave wv owns q-tile
// [blockIdx.y*128 + wv*32, +32) and iterates ALL 64 k-blocks; K/V staged in
// double-buffered LDS (4KB K + 4KB V per buffer) by all 256 threads via
// global_load_lds (2 x gld16/thread/iter), one __syncthreads per iter.
// Cuts L2->CU K/V traffic 4x vs per-wave private streams (R6: 20 TB/s, 58%
// of L2 ceiling, was the stall source). No cross-wave partial merge needed
// (each wave sums full k): no Os/Ls, epilogue writes directly.
// ds_read_b128 at lane*16 = 2-way bank aliasing = free (m136).
// XCD affinity: bh rides blockIdx.x; 32 % 8 == 0 keeps XCD = bh % 8.
__global__ __launch_bounds__(256, 4) void k_attn(
    const _Float16* __restrict__ Q, const _Float16* __restrict__ Kp,
    const _Float16* __restrict__ Vp, const int* __restrict__ mask,
    const int* __restrict__ flag, _Float16* __restrict__ O)
{
    __shared__ _Float16 KV[2 * 4096];  // [buf][K 2048 | V 2048] halves, 16 KB

    const int tid = threadIdx.x;
    const int lane = tid & 63, wv = tid >> 6;
    const int l5 = lane & 31, half = lane >> 5;
    const int bh = blockIdx.x;               // XCD-affine: bh -> XCD bh%8
    const int b = bh >> 4, h = bh & 15;
    const int qb = blockIdx.y * 128 + wv * 32;

    const _Float16* Qb = Q  + (size_t)bh * 2048 * 64;
    const _Float16* Kst = Kp + (size_t)bh * 131072 + tid * 8;  // stage srcs
    const _Float16* Vst = Vp + (size_t)bh * 131072 + tid * 8;

    // Q fragments (B operand of S^T = K*Q^T): n=q=l5, k(dk)=kk*16+half*8+t
    f16x8 qf[4];
#pragma unroll
    for (int kk = 0; kk < 4; ++kk)
        qf[kk] = *(const f16x8*)(Qb + (size_t)(qb + l5) * 64 + kk * 16 + half * 8);

    const f16x2 one2 = {(_Float16)1.f, (_Float16)1.f};

    f32x16 o[2];
#pragma unroll
    for (int nt = 0; nt < 2; ++nt)
#pragma unroll
        for (int r = 0; r < 16; ++r) o[nt][r] = 0.f;
    float l_i = 0.f;

    const bool has_zero = (*flag != 0);

    // ---- prologue: stage k-block 0 into buffer 0 ----
    gld16(Kst, KV + tid * 8);
    gld16(Vst, KV + 2048 + tid * 8);
    __syncthreads();   // compiler emits vmcnt(0) drain before barrier

#pragma unroll 2
    for (int it = 0; it < 64; ++it) {
        const int cur = (it & 1) * 4096;
        // stage next k-block into the other buffer (read last in iter it-1)
        if (it < 63) {
            const int nxt = cur ^ 4096;
            gld16(Kst + (it + 1) * 2048, KV + nxt + tid * 8);
            gld16(Vst + (it + 1) * 2048, KV + nxt + 2048 + tid * 8);
        }

        // fragment reads from current buffer (2-way bank alias = free)
        f16x8 kf[4], vf[4];
#pragma unroll
        for (int kk = 0; kk < 4; ++kk)
            kf[kk] = *(const f16x8*)(KV + cur + (kk * 64 + lane) * 8);
#pragma unroll
        for (int j = 0; j < 4; ++j)
            vf[j] = *(const f16x8*)(KV + cur + 2048 + (j * 64 + lane) * 8);

        // ---- S^T = K * Q^T ----
        f32x16 st;
#pragma unroll
        for (int r = 0; r < 16; ++r) st[r] = 0.f;
        __builtin_amdgcn_s_setprio(1);
        st = MFMA32(kf[0], qf[0], st);
        st = MFMA32(kf[1], qf[1], st);
        st = MFMA32(kf[2], qf[2], st);
        st = MFMA32(kf[3], qf[3], st);
        __builtin_amdgcn_s_setprio(0);

        if (has_zero) {  // never taken for all-ones mask
            const int q = qb + l5;
            const int* mr = mask + ((size_t)b * 2048 + q) * 2048 + it * 32;
            for (int r = 0; r < 16; ++r) {
                const int kk_ = (r & 3) + 8 * (r >> 2) + 4 * half;
                if (mr[kk_] == 0) st[r] = -1e30f;
            }
        }

        // ---- shift-free exp2 softmax: raw v_exp_f32 + pack + fdot2 sum ----
        unsigned u[8];
        float rs = 0.f;
#pragma unroll
        for (int j = 0; j < 8; ++j) {
            const float p0 = EXP2(st[2 * j]);
            const float p1 = EXP2(st[2 * j + 1]);
            u[j] = __builtin_bit_cast(unsigned, __builtin_amdgcn_cvt_pkrtz(p0, p1));
#if __has_builtin(__builtin_amdgcn_fdot2)
            rs = __builtin_amdgcn_fdot2(__builtin_bit_cast(f16x2, u[j]), one2, rs, false);
#else
            rs += p0 + p1;
#endif
        }
        rs += __shfl_xor(rs, 32);   // combine lane-halves (same q)
        l_i += rs;

        // ---- P: C-layout -> A-operand via permlane32_swap half-swap ----
        // swap(A,B): out0 = [A.lo, B.lo], out1 = [A.hi, B.hi]
        u32x2 r02 = __builtin_amdgcn_permlane32_swap(u[0], u[2], false, false);
        u32x2 r13 = __builtin_amdgcn_permlane32_swap(u[1], u[3], false, false);
        u32x2 r46 = __builtin_amdgcn_permlane32_swap(u[4], u[6], false, false);
        u32x2 r57 = __builtin_amdgcn_permlane32_swap(u[5], u[7], false, false);
        i32x4 a0 = { (int)r02[0], (int)r13[0], (int)r02[1], (int)r13[1] };
        i32x4 a1 = { (int)r46[0], (int)r57[0], (int)r46[1], (int)r57[1] };
        f16x8 pa0 = __builtin_bit_cast(f16x8, a0);
        f16x8 pa1 = __builtin_bit_cast(f16x8, a1);

        // ---- O += P * V ----
        __builtin_amdgcn_s_setprio(1);
        o[0] = MFMA32(pa0, vf[0], o[0]);
        o[1] = MFMA32(pa0, vf[1], o[1]);
        o[0] = MFMA32(pa1, vf[2], o[0]);
        o[1] = MFMA32(pa1, vf[3], o[1]);
        __builtin_amdgcn_s_setprio(0);

        __syncthreads();   // buffer handoff (stage drain folded in)
    }

    // ---- normalize and store (no cross-wave merge: full k per wave) ----
    const float linv = 1.f / l_i;    // per lane, row q = qb + l5
#pragma unroll
    for (int r = 0; r < 16; ++r) {
        const int q_loc = (r & 3) + 8 * (r >> 2) + 4 * half;
        const float lv = __shfl(linv, q_loc);
        const int q = qb + q_loc;
        _Float16* orow = O + ((size_t)b * 2048 + q) * 1024 + h * 64;
#pragma unroll
        for (int nt = 0; nt < 2; ++nt)
            orow[nt * 32 + l5] = (_Float16)(o[nt][r] * lv);
    }
}

// ---------------------------------------------------------------------------
extern "C" void kernel_launch(void* const* d_in, const int* in_sizes, int n_in,
                              void* d_out, int out_size, void* d_ws, size_t ws_size,
                              hipStream_t stream) {
    const float* query = (const float*)d_in[0];
    const int*   mask  = (const int*)d_in[1];
    const float* Wq = (const float*)d_in[2]; const float* bq = (const float*)d_in[3];
    const float* Wk = (const float*)d_in[4]; const float* bk = (const float*)d_in[5];
    const float* Wv = (const float*)d_in[6]; const float* bv = (const float*)d_in[7];
    const float* Wo = (const float*)d_in[8]; const float* bo = (const float*)d_in[9];
    float* out = (float*)d_out;

    char* ws = (char*)d_ws;
    _Float16* Xh  = (_Float16*)(ws);                 // 4096x1024, reused as Oh
    _Float16* Wqh = (_Float16*)(ws + 8388608);
    _Float16* Wkh = (_Float16*)(ws + 10485760);
    _Float16* Wvh = (_Float16*)(ws + 12582912);
    _Float16* Woh = (_Float16*)(ws + 14680064);
    _Float16* Qh  = (_Float16*)(ws + 16777216);
    _Float16* Kh  = (_Float16*)(ws + 25165824);      // packed Kp
    _Float16* Vh  = (_Float16*)(ws + 33554432);      // packed Vp
    _Float16* Oh  = Xh;
    int* flag     = (int*)(ws + 41943040);

    (void)hipMemsetAsync(flag, 0, 4, stream);
    k_pre<<<16384, 256, 0, stream>>>(query, Wq, Wk, Wv, Wo,
                                     Xh, Wqh, Wkh, Wvh, Woh, mask, flag);
    k_qkv<<<dim3(24, 32), 256, 0, stream>>>(Xh, Wqh, Wkh, Wvh, bq, bk, bv, Qh, Kh, Vh);
    k_attn<<<dim3(32, 16), 256, 0, stream>>>(Qh, Kh, Vh, mask, flag, Oh);
    k_oproj<<<dim3(16, 32), 256, 0, stream>>>(Oh, Woh, bo, out);
}